// Round 1
// baseline (256.113 us; speedup 1.0000x reference)
//
#include <hip/hip_runtime.h>
#include <stdint.h>

using f32x4  = __attribute__((ext_vector_type(4))) float;
using bf16x8 = __attribute__((ext_vector_type(8))) short;
using ushort8 = __attribute__((ext_vector_type(8))) unsigned short;

#define B_   16384
#define S_   256
#define DIN  2048
#define DFC  1024
#define NB_  10

// f32 -> bf16 round-to-nearest-even
__device__ __forceinline__ unsigned short f2bf(float f) {
  union { float f; unsigned int u; } v; v.f = f;
  unsigned int u = v.u;
  unsigned int r = (u + 0x7FFFu + ((u >> 16) & 1u)) >> 16;
  return (unsigned short)r;
}

// async global->LDS, 16B per lane. LDS dest is wave-uniform base + lane*16.
__device__ __forceinline__ void gload_lds16(const void* g, void* l) {
  __builtin_amdgcn_global_load_lds(
      (const __attribute__((address_space(1))) unsigned int*)g,
      (__attribute__((address_space(3))) unsigned int*)l, 16, 0, 0);
}

// ---------------- K0: W1 (f32, [K=2048][N=1024]) -> Wt (bf16, [N][K]) ----------------
__global__ __launch_bounds__(256)
void convT_kernel(const float* __restrict__ W, unsigned short* __restrict__ Wt) {
  __shared__ unsigned short t[32][33];
  const int tx = threadIdx.x & 31;
  const int ty = threadIdx.x >> 5;          // 0..7
  const int nb = blockIdx.x * 32;           // n base
  const int kb = blockIdx.y * 32;           // k base
#pragma unroll
  for (int i = 0; i < 32; i += 8)
    t[ty + i][tx] = f2bf(W[(size_t)(kb + ty + i) * DFC + nb + tx]);
  __syncthreads();
#pragma unroll
  for (int i = 0; i < 32; i += 8)
    Wt[(size_t)(nb + ty + i) * DIN + kb + tx] = t[tx][ty + i];
}

// ---------------- K1: x = elu(A @ W1 + b1), stored bf16 ----------------
// 128x128 tile, BK=32, 4 waves (2x2 of 64x64). A: f32 reg-staged + cvt; B: global_load_lds.
__global__ __launch_bounds__(256, 2)
void gemm1_kernel(const float* __restrict__ A, const unsigned short* __restrict__ Bt,
                  const float* __restrict__ b1, unsigned short* __restrict__ X) {
  __shared__ unsigned short sA[128 * 40];   // stride 40 elems = 80B (16B-aligned, ~2-way banks)
  __shared__ unsigned short sB[128 * 32];   // linear (global_load_lds writes base+lane*16)
  const int tid  = threadIdx.x;
  const int wave = tid >> 6, lane = tid & 63;
  // XCD-chunked swizzle: 8 consecutive logical ntiles (sharing one A row-panel) -> same XCD.
  const int b    = blockIdx.x;              // 1024 blocks
  const int xcd  = b & 7, slot = b >> 3;    // HW round-robins b%8 across XCDs
  const int mtile = xcd * 16 + (slot >> 3); // 0..127
  const int ntile = slot & 7;               // 0..7
  const int rowBase = mtile * 128, colBase = ntile * 128;
  const int wr = wave >> 1, wc = wave & 1;

  f32x4 acc[4][4] = {};

  // A staging: thread covers row tid/2, k-half (tid&1)*16 (16 elems = 64B f32)
  const int ar = tid >> 1, ah = (tid & 1) * 16;
  const float* Ap = A + (size_t)(rowBase + ar) * DIN + ah;
  // B staging: lane l of wave w -> LDS elems (w*512 + l*8), i.e. row w*16+l/4, kcol (l&3)*8
  const int brow = wave * 16 + (lane >> 2);
  const int bkc  = (lane & 3) * 8;
  const unsigned short* Bp0 = Bt + (size_t)(colBase + brow) * DIN + bkc;
  const unsigned short* Bp1 = Bp0 + (size_t)64 * DIN;
  unsigned short* sBb = &sB[wave * 512];
  const int frow = lane & 15, fks = (lane >> 4) * 8;

  for (int kk = 0; kk < DIN; kk += 32) {
    f32x4 a0 = *(const f32x4*)(Ap + kk);
    f32x4 a1 = *(const f32x4*)(Ap + kk + 4);
    f32x4 a2 = *(const f32x4*)(Ap + kk + 8);
    f32x4 a3 = *(const f32x4*)(Ap + kk + 12);
    gload_lds16(Bp0 + kk, sBb);
    gload_lds16(Bp1 + kk, sBb + 2048);
    ushort8 lo, hi;
    lo[0] = f2bf(a0[0]); lo[1] = f2bf(a0[1]); lo[2] = f2bf(a0[2]); lo[3] = f2bf(a0[3]);
    lo[4] = f2bf(a1[0]); lo[5] = f2bf(a1[1]); lo[6] = f2bf(a1[2]); lo[7] = f2bf(a1[3]);
    hi[0] = f2bf(a2[0]); hi[1] = f2bf(a2[1]); hi[2] = f2bf(a2[2]); hi[3] = f2bf(a2[3]);
    hi[4] = f2bf(a3[0]); hi[5] = f2bf(a3[1]); hi[6] = f2bf(a3[2]); hi[7] = f2bf(a3[3]);
    *(ushort8*)&sA[ar * 40 + ah]     = lo;
    *(ushort8*)&sA[ar * 40 + ah + 8] = hi;
    __syncthreads();
    bf16x8 af[4], bfr[4];
#pragma unroll
    for (int m = 0; m < 4; ++m)
      af[m] = *(const bf16x8*)&sA[(wr * 64 + m * 16 + frow) * 40 + fks];
#pragma unroll
    for (int n = 0; n < 4; ++n)
      bfr[n] = *(const bf16x8*)&sB[(wc * 64 + n * 16 + frow) * 32 + fks];
#pragma unroll
    for (int m = 0; m < 4; ++m)
#pragma unroll
      for (int n = 0; n < 4; ++n)
        acc[m][n] = __builtin_amdgcn_mfma_f32_16x16x32_bf16(af[m], bfr[n], acc[m][n], 0, 0, 0);
    __syncthreads();
  }

  // epilogue: C/D layout col = lane&15, row = (lane>>4)*4 + reg
  const int er0 = rowBase + wr * 64 + (lane >> 4) * 4;
  const int ec0 = colBase + wc * 64 + (lane & 15);
  float bv[4];
#pragma unroll
  for (int n = 0; n < 4; ++n) bv[n] = b1[ec0 + n * 16];
#pragma unroll
  for (int m = 0; m < 4; ++m)
#pragma unroll
    for (int n = 0; n < 4; ++n)
#pragma unroll
      for (int r = 0; r < 4; ++r) {
        float v = acc[m][n][r] + bv[n];
        v = v > 0.f ? v : expm1f(v);
        X[(size_t)(er0 + m * 16 + r) * DFC + ec0 + n * 16] = f2bf(v);
      }
}

// ---------------- K2: shape_params = x @ w_shape + b_shape -> d_out (mode | log_std) ----------------
// 64-row tiles, N padded 20->32 (2 n-frags), K=1024. x via global_load_lds; w tile reg-staged per step.
__global__ __launch_bounds__(256)
void gemm2_kernel(const unsigned short* __restrict__ X, const float* __restrict__ Wsh,
                  const float* __restrict__ bsh, float* __restrict__ out) {
  __shared__ unsigned short sX[64 * 32];    // linear for global_load_lds
  __shared__ unsigned short sW[32 * 40];    // [j][k] stride 40 (80B)
  const int tid  = threadIdx.x;
  const int wave = tid >> 6, lane = tid & 63;
  const int rowB = blockIdx.x * 64;
  f32x4 acc[2] = {};
  const unsigned short* xp = X + (size_t)(rowB + (tid >> 2)) * DFC + (tid & 3) * 8;
  unsigned short* sXb = &sX[wave * 512];
  const int frow = lane & 15, fks = (lane >> 4) * 8;

  for (int kk = 0; kk < DFC; kk += 32) {
    gload_lds16(xp + kk, sXb);
    for (int idx = tid; idx < 32 * 40; idx += 256) {
      int j = idx / 40, ki = idx - j * 40;
      sW[idx] = (j < 20 && ki < 32) ? f2bf(Wsh[(size_t)(kk + ki) * 20 + j]) : (unsigned short)0;
    }
    __syncthreads();
    bf16x8 xa  = *(const bf16x8*)&sX[(wave * 16 + frow) * 32 + fks];
    bf16x8 w0  = *(const bf16x8*)&sW[(frow) * 40 + fks];
    bf16x8 w1f = *(const bf16x8*)&sW[(16 + frow) * 40 + fks];
    acc[0] = __builtin_amdgcn_mfma_f32_16x16x32_bf16(xa, w0,  acc[0], 0, 0, 0);
    acc[1] = __builtin_amdgcn_mfma_f32_16x16x32_bf16(xa, w1f, acc[1], 0, 0, 0);
    __syncthreads();
  }
  const int r0 = rowB + wave * 16 + (lane >> 4) * 4;
  const int c0 = lane & 15;
#pragma unroll
  for (int n = 0; n < 2; ++n) {
    int j = n * 16 + c0;
    if (j < 20) {
      float bj = bsh[j];
      int jj = j < 10 ? j : j - 10;
      size_t base = (j < 10) ? (size_t)0 : (size_t)B_ * NB_;
#pragma unroll
      for (int r = 0; r < 4; ++r)
        out[base + (size_t)(r0 + r) * NB_ + jj] = acc[n][r] + bj;
    }
  }
}

// ---------------- K3: samples = mode + exp(log_std) * noise ----------------
// one wave per row; float4 loads/stores; mode/exp(ls) broadcast from tiny LDS arrays.
__global__ __launch_bounds__(256)
void sample_kernel(const float* __restrict__ noise, float* __restrict__ out) {
  __shared__ float sm[4][NB_], se[4][NB_];
  const int tid  = threadIdx.x;
  const int wave = tid >> 6, lane = tid & 63;
  const int row  = blockIdx.x * 4 + wave;
  if (lane < NB_) {
    sm[wave][lane] = out[(size_t)row * NB_ + lane];
    se[wave][lane] = expf(out[(size_t)B_ * NB_ + (size_t)row * NB_ + lane]);
  }
  __syncthreads();
  const f32x4* np4 = (const f32x4*)(noise + (size_t)row * (S_ * NB_));
  f32x4*       op4 = (f32x4*)(out + (size_t)2 * B_ * NB_ + (size_t)row * (S_ * NB_));
#pragma unroll
  for (int it = 0; it < (S_ * NB_) / 256; ++it) {   // 10 iters
    f32x4 nv = np4[it * 64 + lane];
    int j0 = (lane * 4 + it * 6) % 10;
    int j1 = j0 + 1; if (j1 >= 10) j1 -= 10;
    int j2 = j1 + 1; if (j2 >= 10) j2 -= 10;
    int j3 = j2 + 1; if (j3 >= 10) j3 -= 10;
    f32x4 r;
    r[0] = sm[wave][j0] + se[wave][j0] * nv[0];
    r[1] = sm[wave][j1] + se[wave][j1] * nv[1];
    r[2] = sm[wave][j2] + se[wave][j2] * nv[2];
    r[3] = sm[wave][j3] + se[wave][j3] * nv[3];
    op4[it * 64 + lane] = r;
  }
}

extern "C" void kernel_launch(void* const* d_in, const int* in_sizes, int n_in,
                              void* d_out, int out_size, void* d_ws, size_t ws_size,
                              hipStream_t stream) {
  const float* A     = (const float*)d_in[0];  // [16384][2048]
  const float* W1    = (const float*)d_in[1];  // [2048][1024]
  const float* b1    = (const float*)d_in[2];  // [1024]
  const float* Wsh   = (const float*)d_in[3];  // [1024][20]
  const float* bsh   = (const float*)d_in[4];  // [20]
  const float* noise = (const float*)d_in[5];  // [16384][256][10]
  float* out = (float*)d_out;                  // mode | log_std | samples

  unsigned short* Wt = (unsigned short*)d_ws;                      // bf16 [1024][2048] = 4 MB
  unsigned short* X  = (unsigned short*)d_ws + (size_t)DFC * DIN;  // bf16 [16384][1024] = 33.5 MB

  convT_kernel<<<dim3(DFC / 32, DIN / 32), 256, 0, stream>>>(W1, Wt);
  gemm1_kernel<<<dim3((B_ / 128) * (DFC / 128)), 256, 0, stream>>>(A, Wt, b1, X);
  gemm2_kernel<<<dim3(B_ / 64), 256, 0, stream>>>(X, Wsh, bsh, out);
  sample_kernel<<<dim3(B_ / 4), 256, 0, stream>>>(noise, out);
}

// Round 2
// 228.457 us; speedup vs baseline: 1.1211x; 1.1211x over previous
//
#include <hip/hip_runtime.h>
#include <stdint.h>

using f32x4  = __attribute__((ext_vector_type(4))) float;
using bf16x8 = __attribute__((ext_vector_type(8))) short;
using ushort8 = __attribute__((ext_vector_type(8))) unsigned short;

#define B_   16384
#define S_   256
#define DIN  2048
#define DFC  1024
#define NB_  10

// f32 -> bf16 round-to-nearest-even
__device__ __forceinline__ unsigned short f2bf(float f) {
  union { float f; unsigned int u; } v; v.f = f;
  unsigned int u = v.u;
  unsigned int r = (u + 0x7FFFu + ((u >> 16) & 1u)) >> 16;
  return (unsigned short)r;
}

// async global->LDS, 16B per lane. LDS dest is wave-uniform base + lane*16.
__device__ __forceinline__ void gload_lds16(const void* g, void* l) {
  __builtin_amdgcn_global_load_lds(
      (const __attribute__((address_space(1))) unsigned int*)g,
      (__attribute__((address_space(3))) unsigned int*)l, 16, 0, 0);
}

// ---------------- K0a: W1 (f32, [K=2048][N=1024]) -> Wt (bf16, [N][K]) ----------------
__global__ __launch_bounds__(256)
void convT_kernel(const float* __restrict__ W, unsigned short* __restrict__ Wt) {
  __shared__ unsigned short t[32][33];
  const int tx = threadIdx.x & 31;
  const int ty = threadIdx.x >> 5;          // 0..7
  const int nb = blockIdx.x * 32;           // n base
  const int kb = blockIdx.y * 32;           // k base
#pragma unroll
  for (int i = 0; i < 32; i += 8)
    t[ty + i][tx] = f2bf(W[(size_t)(kb + ty + i) * DFC + nb + tx]);
  __syncthreads();
#pragma unroll
  for (int i = 0; i < 32; i += 8)
    Wt[(size_t)(nb + ty + i) * DIN + kb + tx] = t[tx][ty + i];
}

// ---------------- K0b: A (f32 [16384][2048]) -> Ab (bf16, same layout) ----------------
__global__ __launch_bounds__(256)
void convA_kernel(const float* __restrict__ A, unsigned short* __restrict__ Ab) {
  const size_t total = (size_t)B_ * DIN;
  size_t idx = ((size_t)blockIdx.x * 256 + threadIdx.x) * 8;
  const size_t stride = (size_t)gridDim.x * 256 * 8;
  for (; idx < total; idx += stride) {
    f32x4 a = *(const f32x4*)(A + idx);
    f32x4 b = *(const f32x4*)(A + idx + 4);
    ushort8 o;
    o[0] = f2bf(a[0]); o[1] = f2bf(a[1]); o[2] = f2bf(a[2]); o[3] = f2bf(a[3]);
    o[4] = f2bf(b[0]); o[5] = f2bf(b[1]); o[6] = f2bf(b[2]); o[7] = f2bf(b[3]);
    *(ushort8*)(Ab + idx) = o;
  }
}

// ---------------- K1: x = elu(Ab @ Wt^T + b1), stored bf16 ----------------
// 128x128 tile, BK=64, 4 waves (2x2 of 64x64). Both operands via global_load_lds
// (linear LDS dest); bank-conflict-free reads via both-sides XOR swizzle:
// LDS chunk (row r, c) holds global 16B-chunk c^(r&7) of row r (rule #21).
__global__ __launch_bounds__(256)
void gemm1_kernel(const unsigned short* __restrict__ Ab, const unsigned short* __restrict__ Bt,
                  const float* __restrict__ b1, unsigned short* __restrict__ X) {
  __shared__ unsigned short sA[128 * 64];   // 16 KB, linear for global_load_lds
  __shared__ unsigned short sB[128 * 64];   // 16 KB
  const int tid  = threadIdx.x;
  const int wave = tid >> 6, lane = tid & 63;
  // XCD-chunked swizzle: 8 consecutive slots (sharing one A row-panel) -> same XCD.
  const int b    = blockIdx.x;              // 1024 blocks
  const int xcd  = b & 7, slot = b >> 3;
  const int mtile = xcd * 16 + (slot >> 3); // 0..127
  const int ntile = slot & 7;               // 0..7
  const int rowBase = mtile * 128, colBase = ntile * 128;
  const int wr = wave >> 1, wc = wave & 1;

  f32x4 acc[4][4] = {};

  // Staging: instr i of wave w covers LDS chunks [(w*4+i)*64, +64); lane l -> chunk id.
  // id = (w*4+i)*64 + l -> row = w*32 + i*8 + (l>>3), col-chunk c = l&7.
  // Source chunk (inverse swizzle) = c ^ (row&7) = (l&7) ^ (l>>3)  [row&7 == l>>3].
  const int srow = wave * 32 + (lane >> 3);
  const int schk = (lane & 7) ^ (lane >> 3);
  const unsigned short* pA = Ab + (size_t)(rowBase + srow) * DIN + schk * 8;
  const unsigned short* pB = Bt + (size_t)(colBase + srow) * DIN + schk * 8;

  const int frow = lane & 15, hi = lane >> 4, s7 = lane & 7;  // s7 == frow&7 for reads

  for (int kk = 0; kk < DIN; kk += 64) {
#pragma unroll
    for (int i = 0; i < 4; ++i) {
      gload_lds16(pA + (size_t)i * 8 * DIN + kk, &sA[(wave * 4 + i) * 512]);
      gload_lds16(pB + (size_t)i * 8 * DIN + kk, &sB[(wave * 4 + i) * 512]);
    }
    __syncthreads();
#pragma unroll
    for (int ks = 0; ks < 2; ++ks) {
      const int rchk = ((ks * 4 + hi) ^ (frow & 7)) * 8;
      bf16x8 af[4], bfr[4];
#pragma unroll
      for (int m = 0; m < 4; ++m)
        af[m] = *(const bf16x8*)&sA[(wr * 64 + m * 16 + frow) * 64 + rchk];
#pragma unroll
      for (int n = 0; n < 4; ++n)
        bfr[n] = *(const bf16x8*)&sB[(wc * 64 + n * 16 + frow) * 64 + rchk];
#pragma unroll
      for (int m = 0; m < 4; ++m)
#pragma unroll
        for (int n = 0; n < 4; ++n)
          acc[m][n] = __builtin_amdgcn_mfma_f32_16x16x32_bf16(af[m], bfr[n], acc[m][n], 0, 0, 0);
    }
    __syncthreads();
  }

  // epilogue: C/D layout col = lane&15, row = (lane>>4)*4 + reg
  const int er0 = rowBase + wr * 64 + (lane >> 4) * 4;
  const int ec0 = colBase + wc * 64 + (lane & 15);
  float bv[4];
#pragma unroll
  for (int n = 0; n < 4; ++n) bv[n] = b1[ec0 + n * 16];
#pragma unroll
  for (int m = 0; m < 4; ++m)
#pragma unroll
    for (int n = 0; n < 4; ++n)
#pragma unroll
      for (int r = 0; r < 4; ++r) {
        float v = acc[m][n][r] + bv[n];
        v = v > 0.f ? v : expm1f(v);
        X[(size_t)(er0 + m * 16 + r) * DFC + ec0 + n * 16] = f2bf(v);
      }
}

// ---------------- K2: shape_params = x @ w_shape + b_shape -> d_out (mode | log_std) ----------------
__global__ __launch_bounds__(256)
void gemm2_kernel(const unsigned short* __restrict__ X, const float* __restrict__ Wsh,
                  const float* __restrict__ bsh, float* __restrict__ out) {
  __shared__ unsigned short sX[64 * 32];    // linear for global_load_lds
  __shared__ unsigned short sW[32 * 40];    // [j][k] stride 40 (80B)
  const int tid  = threadIdx.x;
  const int wave = tid >> 6, lane = tid & 63;
  const int rowB = blockIdx.x * 64;
  f32x4 acc[2] = {};
  const unsigned short* xp = X + (size_t)(rowB + (tid >> 2)) * DFC + (tid & 3) * 8;
  unsigned short* sXb = &sX[wave * 512];
  const int frow = lane & 15, fks = (lane >> 4) * 8;

  for (int kk = 0; kk < DFC; kk += 32) {
    gload_lds16(xp + kk, sXb);
    for (int idx = tid; idx < 32 * 40; idx += 256) {
      int j = idx / 40, ki = idx - j * 40;
      sW[idx] = (j < 20 && ki < 32) ? f2bf(Wsh[(size_t)(kk + ki) * 20 + j]) : (unsigned short)0;
    }
    __syncthreads();
    bf16x8 xa  = *(const bf16x8*)&sX[(wave * 16 + frow) * 32 + fks];
    bf16x8 w0  = *(const bf16x8*)&sW[(frow) * 40 + fks];
    bf16x8 w1f = *(const bf16x8*)&sW[(16 + frow) * 40 + fks];
    acc[0] = __builtin_amdgcn_mfma_f32_16x16x32_bf16(xa, w0,  acc[0], 0, 0, 0);
    acc[1] = __builtin_amdgcn_mfma_f32_16x16x32_bf16(xa, w1f, acc[1], 0, 0, 0);
    __syncthreads();
  }
  const int r0 = rowB + wave * 16 + (lane >> 4) * 4;
  const int c0 = lane & 15;
#pragma unroll
  for (int n = 0; n < 2; ++n) {
    int j = n * 16 + c0;
    if (j < 20) {
      float bj = bsh[j];
      int jj = j < 10 ? j : j - 10;
      size_t base = (j < 10) ? (size_t)0 : (size_t)B_ * NB_;
#pragma unroll
      for (int r = 0; r < 4; ++r)
        out[base + (size_t)(r0 + r) * NB_ + jj] = acc[n][r] + bj;
    }
  }
}

// ---------------- K3: samples = mode + exp(log_std) * noise ----------------
__global__ __launch_bounds__(256)
void sample_kernel(const float* __restrict__ noise, float* __restrict__ out) {
  __shared__ float sm[4][NB_], se[4][NB_];
  const int tid  = threadIdx.x;
  const int wave = tid >> 6, lane = tid & 63;
  const int row  = blockIdx.x * 4 + wave;
  if (lane < NB_) {
    sm[wave][lane] = out[(size_t)row * NB_ + lane];
    se[wave][lane] = expf(out[(size_t)B_ * NB_ + (size_t)row * NB_ + lane]);
  }
  __syncthreads();
  const f32x4* np4 = (const f32x4*)(noise + (size_t)row * (S_ * NB_));
  f32x4*       op4 = (f32x4*)(out + (size_t)2 * B_ * NB_ + (size_t)row * (S_ * NB_));
#pragma unroll
  for (int it = 0; it < (S_ * NB_) / 256; ++it) {   // 10 iters
    f32x4 nv = np4[it * 64 + lane];
    int j0 = (lane * 4 + it * 6) % 10;
    int j1 = j0 + 1; if (j1 >= 10) j1 -= 10;
    int j2 = j1 + 1; if (j2 >= 10) j2 -= 10;
    int j3 = j2 + 1; if (j3 >= 10) j3 -= 10;
    f32x4 r;
    r[0] = sm[wave][j0] + se[wave][j0] * nv[0];
    r[1] = sm[wave][j1] + se[wave][j1] * nv[1];
    r[2] = sm[wave][j2] + se[wave][j2] * nv[2];
    r[3] = sm[wave][j3] + se[wave][j3] * nv[3];
    op4[it * 64 + lane] = r;
  }
}

extern "C" void kernel_launch(void* const* d_in, const int* in_sizes, int n_in,
                              void* d_out, int out_size, void* d_ws, size_t ws_size,
                              hipStream_t stream) {
  const float* A     = (const float*)d_in[0];  // [16384][2048]
  const float* W1    = (const float*)d_in[1];  // [2048][1024]
  const float* b1    = (const float*)d_in[2];  // [1024]
  const float* Wsh   = (const float*)d_in[3];  // [1024][20]
  const float* bsh   = (const float*)d_in[4];  // [20]
  const float* noise = (const float*)d_in[5];  // [16384][256][10]
  float* out = (float*)d_out;                  // mode | log_std | samples

  unsigned short* Wt = (unsigned short*)d_ws;                      // bf16 [1024][2048] = 4 MB
  unsigned short* X  = (unsigned short*)d_ws + (size_t)DFC * DIN;  // bf16 [16384][1024] = 33.5 MB
  // Ab (bf16 A, 64 MB): put in ws if it fits, else stash in d_out's samples
  // region (168 MB; written before gemm1 reads it, overwritten by sample_kernel).
  const size_t wsNeed = (size_t)DFC * DIN * 2 + (size_t)B_ * DFC * 2 + (size_t)B_ * DIN * 2;
  unsigned short* Ab = (ws_size >= wsNeed)
      ? (unsigned short*)d_ws + (size_t)DFC * DIN + (size_t)B_ * DFC
      : (unsigned short*)(out + (size_t)2 * B_ * NB_);

  convT_kernel<<<dim3(DFC / 32, DIN / 32), 256, 0, stream>>>(W1, Wt);
  convA_kernel<<<dim3(2048), 256, 0, stream>>>(A, Ab);
  gemm1_kernel<<<dim3((B_ / 128) * (DFC / 128)), 256, 0, stream>>>(Ab, Wt, b1, X);
  gemm2_kernel<<<dim3(B_ / 64), 256, 0, stream>>>(X, Wsh, bsh, out);
  sample_kernel<<<dim3(B_ / 4), 256, 0, stream>>>(noise, out);
}